// Round 1
// baseline (1310.316 us; speedup 1.0000x reference)
//
#include <hip/hip_runtime.h>
#include <hip/hip_bf16.h>

#define T_TOK 8192
#define H_DIM 1024
#define I_DIM 4096
#define NEXP 8

typedef __bf16 bf16x8 __attribute__((ext_vector_type(8)));
typedef float f32x4 __attribute__((ext_vector_type(4)));
typedef unsigned short u16;

#define AS3(p) ((__attribute__((address_space(3))) void*)(p))
#define AS1(p) ((const __attribute__((address_space(1))) void*)(p))
#define GLDS16(src, dst) __builtin_amdgcn_global_load_lds(AS1(src), AS3(dst), 16, 0, 0)

__device__ __forceinline__ u16 f2bf(float f) {
  union { float f; unsigned u; } c; c.f = f;
  unsigned u = c.u;
  return (u16)((u + 0x7FFFu + ((u >> 16) & 1u)) >> 16);
}

__global__ void init_counts(int* counts) {
  if (threadIdx.x < NEXP) counts[threadIdx.x] = 0;
}

__global__ void zero_f32(float* p, int n) {
  int i = blockIdx.x * blockDim.x + threadIdx.x;
  int s = gridDim.x * blockDim.x;
  for (; i < n; i += s) p[i] = 0.f;
}

__global__ void cvt_bf16(const float4* __restrict__ in, u16* __restrict__ out, int n4) {
  int i = blockIdx.x * blockDim.x + threadIdx.x;
  int s = gridDim.x * blockDim.x;
  for (; i < n4; i += s) {
    float4 v = in[i];
    ushort4 o;
    o.x = f2bf(v.x); o.y = f2bf(v.y); o.z = f2bf(v.z); o.w = f2bf(v.w);
    *(ushort4*)(out + (size_t)i * 4) = o;
  }
}

// One block per token; 8 waves, wave e computes logit_e in fp64.
__global__ __launch_bounds__(512) void router_kernel(
    const float* __restrict__ x, const float* __restrict__ rw,
    float* __restrict__ probs, int* __restrict__ tok, float* __restrict__ wgt,
    int* __restrict__ counts)
{
  int t = blockIdx.x;
  int w = threadIdx.x >> 6, lane = threadIdx.x & 63;
  const float* xr = x + (size_t)t * H_DIM;
  const float* wr = rw + (size_t)w * H_DIM;
  double acc = 0.0;
  #pragma unroll
  for (int j = 0; j < H_DIM / 64; ++j) {
    int h = lane + 64 * j;
    acc += (double)xr[h] * (double)wr[h];
  }
  #pragma unroll
  for (int off = 32; off > 0; off >>= 1) acc += __shfl_down(acc, off);
  __shared__ double logits[NEXP];
  if (lane == 0) logits[w] = acc;
  __syncthreads();
  if (threadIdx.x == 0) {
    int i1 = 0;
    #pragma unroll
    for (int e = 1; e < NEXP; ++e) if (logits[e] > logits[i1]) i1 = e;
    int i2 = (i1 == 0) ? 1 : 0;
    #pragma unroll
    for (int e = 0; e < NEXP; ++e) {
      if (e == i1) continue;
      if (logits[e] > logits[i2]) i2 = e;
    }
    double l1 = logits[i1], l2 = logits[i2];
    float w1 = (float)(1.0 / (1.0 + exp(l2 - l1)));
    float w2 = 1.0f - w1;
    double m = l1, s = 0.0, p[NEXP];
    #pragma unroll
    for (int e = 0; e < NEXP; ++e) { p[e] = exp(logits[e] - m); s += p[e]; }
    #pragma unroll
    for (int e = 0; e < NEXP; ++e) probs[(size_t)t * NEXP + e] = (float)(p[e] / s);
    int p1 = atomicAdd(&counts[i1], 1);
    tok[i1 * T_TOK + p1] = t; wgt[i1 * T_TOK + p1] = w1;
    int p2 = atomicAdd(&counts[i2], 1);
    tok[i2 * T_TOK + p2] = t; wgt[i2 * T_TOK + p2] = w2;
  }
}

__global__ void scan_offsets(const int* __restrict__ counts, int* __restrict__ off) {
  if (threadIdx.x == 0) {
    int s = 0;
    for (int e = 0; e < NEXP; ++e) { off[e] = s; s += counts[e]; }
  }
}

// Fused gate/up GEMM + SwiGLU.  A: gathered tokens [cnt,1024] bf16.
// B: wg[e],wu[e] [4096,1024] bf16 (N,K row-major).  Out: h_bf [pos,4096] bf16.
__global__ __launch_bounds__(256) void gemm1_kernel(
    const u16* __restrict__ x_bf, const u16* __restrict__ wg_bf,
    const u16* __restrict__ wu_bf, u16* __restrict__ h_bf,
    const int* __restrict__ tok, const int* __restrict__ counts,
    const int* __restrict__ off)
{
  int e = blockIdx.z;
  int cnt = counts[e];
  int mb = blockIdx.y * 128;
  if (mb >= cnt) return;
  int nb = blockIdx.x * 128;
  int tid = threadIdx.x;

  __shared__ u16 lds[3 * 128 * 32];
  u16* ldsA = lds;
  u16* ldsG = lds + 4096;
  u16* ldsU = lds + 8192;

  int srow = tid >> 2;          // 0..63
  int skp  = (tid & 3) * 8;     // k elems
  int t0 = tok[e * T_TOK + min(mb + srow, cnt - 1)];
  int t1 = tok[e * T_TOK + min(mb + srow + 64, cnt - 1)];
  const u16* a0 = x_bf + (size_t)t0 * H_DIM + skp;
  const u16* a1 = x_bf + (size_t)t1 * H_DIM + skp;
  const u16* g0 = wg_bf + (size_t)e * I_DIM * H_DIM + (size_t)(nb + srow) * H_DIM + skp;
  const u16* g1 = g0 + (size_t)64 * H_DIM;
  const u16* u0 = wu_bf + (size_t)e * I_DIM * H_DIM + (size_t)(nb + srow) * H_DIM + skp;
  const u16* u1 = u0 + (size_t)64 * H_DIM;

  int w = tid >> 6, lane = tid & 63;
  int wr = (w >> 1) * 64, wc = (w & 1) * 64;
  int lr = lane & 15, lk = (lane >> 4) * 8;

  f32x4 accg[4][4] = {};
  f32x4 accu[4][4] = {};

  for (int kk = 0; kk < H_DIM; kk += 32) {
    GLDS16(a0 + kk, ldsA + tid * 8);
    GLDS16(a1 + kk, ldsA + 2048 + tid * 8);
    GLDS16(g0 + kk, ldsG + tid * 8);
    GLDS16(g1 + kk, ldsG + 2048 + tid * 8);
    GLDS16(u0 + kk, ldsU + tid * 8);
    GLDS16(u1 + kk, ldsU + 2048 + tid * 8);
    __syncthreads();
    bf16x8 af[4], gf[4], uf[4];
    #pragma unroll
    for (int m = 0; m < 4; ++m)
      af[m] = *(const bf16x8*)&ldsA[(wr + m * 16 + lr) * 32 + lk];
    #pragma unroll
    for (int n = 0; n < 4; ++n) {
      gf[n] = *(const bf16x8*)&ldsG[(wc + n * 16 + lr) * 32 + lk];
      uf[n] = *(const bf16x8*)&ldsU[(wc + n * 16 + lr) * 32 + lk];
    }
    #pragma unroll
    for (int m = 0; m < 4; ++m) {
      #pragma unroll
      for (int n = 0; n < 4; ++n) {
        accg[m][n] = __builtin_amdgcn_mfma_f32_16x16x32_bf16(af[m], gf[n], accg[m][n], 0, 0, 0);
        accu[m][n] = __builtin_amdgcn_mfma_f32_16x16x32_bf16(af[m], uf[n], accu[m][n], 0, 0, 0);
      }
    }
    __syncthreads();
  }

  int ofs = off[e];
  #pragma unroll
  for (int m = 0; m < 4; ++m) {
    #pragma unroll
    for (int r = 0; r < 4; ++r) {
      int row = mb + wr + m * 16 + (lane >> 4) * 4 + r;
      if (row < cnt) {
        size_t base = (size_t)(ofs + row) * I_DIM + nb + wc;
        #pragma unroll
        for (int n = 0; n < 4; ++n) {
          float g = accg[m][n][r];
          float u = accu[m][n][r];
          float sg = g / (1.f + __expf(-g));
          h_bf[base + n * 16 + lr] = f2bf(sg * u);
        }
      }
    }
  }
}

// GEMM2: y = h @ wd[e]^T, weighted atomic scatter into out.
__global__ __launch_bounds__(256) void gemm2_kernel(
    const u16* __restrict__ h_bf, const u16* __restrict__ wd_bf,
    float* __restrict__ out, const int* __restrict__ tok,
    const float* __restrict__ wgt, const int* __restrict__ counts,
    const int* __restrict__ off)
{
  int e = blockIdx.z;
  int cnt = counts[e];
  int mb = blockIdx.y * 128;
  if (mb >= cnt) return;
  int nb = blockIdx.x * 128;
  int tid = threadIdx.x;
  int ofs = off[e];

  __shared__ u16 lds[2 * 128 * 32];
  u16* ldsA = lds;
  u16* ldsB = lds + 4096;

  int srow = tid >> 2, skp = (tid & 3) * 8;
  int r0 = min(mb + srow, cnt - 1);
  int r1 = min(mb + srow + 64, cnt - 1);
  const u16* a0 = h_bf + (size_t)(ofs + r0) * I_DIM + skp;
  const u16* a1 = h_bf + (size_t)(ofs + r1) * I_DIM + skp;
  const u16* b0 = wd_bf + (size_t)e * H_DIM * I_DIM + (size_t)(nb + srow) * I_DIM + skp;
  const u16* b1 = b0 + (size_t)64 * I_DIM;

  int w = tid >> 6, lane = tid & 63;
  int wr = (w >> 1) * 64, wc = (w & 1) * 64;
  int lr = lane & 15, lk = (lane >> 4) * 8;

  f32x4 acc[4][4] = {};
  for (int kk = 0; kk < I_DIM; kk += 32) {
    GLDS16(a0 + kk, ldsA + tid * 8);
    GLDS16(a1 + kk, ldsA + 2048 + tid * 8);
    GLDS16(b0 + kk, ldsB + tid * 8);
    GLDS16(b1 + kk, ldsB + 2048 + tid * 8);
    __syncthreads();
    bf16x8 af[4], bfr[4];
    #pragma unroll
    for (int m = 0; m < 4; ++m)
      af[m] = *(const bf16x8*)&ldsA[(wr + m * 16 + lr) * 32 + lk];
    #pragma unroll
    for (int n = 0; n < 4; ++n)
      bfr[n] = *(const bf16x8*)&ldsB[(wc + n * 16 + lr) * 32 + lk];
    #pragma unroll
    for (int m = 0; m < 4; ++m) {
      #pragma unroll
      for (int n = 0; n < 4; ++n)
        acc[m][n] = __builtin_amdgcn_mfma_f32_16x16x32_bf16(af[m], bfr[n], acc[m][n], 0, 0, 0);
    }
    __syncthreads();
  }

  #pragma unroll
  for (int m = 0; m < 4; ++m) {
    #pragma unroll
    for (int r = 0; r < 4; ++r) {
      int pos = mb + wr + m * 16 + (lane >> 4) * 4 + r;
      if (pos < cnt) {
        int t = tok[e * T_TOK + pos];
        float wt = wgt[e * T_TOK + pos];
        size_t base = (size_t)t * H_DIM + nb + wc;
        #pragma unroll
        for (int n = 0; n < 4; ++n)
          atomicAdd(&out[base + n * 16 + lr], wt * acc[m][n][r]);
      }
    }
  }
}

__global__ __launch_bounds__(512) void finalize_kernel(
    const float* __restrict__ probs, float* __restrict__ aux_out)
{
  __shared__ double part[512];
  int tid = threadIdx.x;
  int e = tid & 7;
  double s = 0.0;
  for (int t = tid >> 3; t < T_TOK; t += 64) s += probs[(size_t)t * NEXP + e];
  part[tid] = s;
  __syncthreads();
  if (tid < 8) {
    double u = 0.0;
    for (int i = tid; i < 512; i += 8) u += part[i];
    part[tid] = u;
  }
  __syncthreads();
  if (tid == 0) {
    double tot = 0.0;
    for (int k = 0; k < 8; ++k) tot += part[k];
    double aux = 0.0;
    for (int k = 0; k < 8; ++k) {
      double d = part[k] / tot - 0.125;
      aux += d * d;
    }
    aux_out[0] = (float)(0.01 * aux / 8.0);
  }
}

extern "C" void kernel_launch(void* const* d_in, const int* in_sizes, int n_in,
                              void* d_out, int out_size, void* d_ws, size_t ws_size,
                              hipStream_t stream) {
  const float* x  = (const float*)d_in[0];
  const float* rw = (const float*)d_in[1];
  const float* wg = (const float*)d_in[2];
  const float* wu = (const float*)d_in[3];
  const float* wd = (const float*)d_in[4];
  float* out = (float*)d_out;

  char* ws = (char*)d_ws;
  const size_t SZ_X  = (size_t)T_TOK * H_DIM * 2;            // 16 MB
  const size_t SZ_W  = (size_t)NEXP * I_DIM * H_DIM * 2;     // 64 MB each
  const size_t SZ_H  = (size_t)(2 * T_TOK + 128) * I_DIM * 2;
  u16* x_bf  = (u16*)(ws);
  u16* wg_bf = (u16*)(ws + SZ_X);
  u16* wu_bf = (u16*)(ws + SZ_X + SZ_W);
  u16* wd_bf = (u16*)(ws + SZ_X + 2 * SZ_W);
  u16* h_bf  = (u16*)(ws + SZ_X + 3 * SZ_W);
  char* tail = ws + SZ_X + 3 * SZ_W + SZ_H;
  float* probs = (float*)tail;
  int*   tok   = (int*)(tail + 262144);
  float* wgt   = (float*)(tail + 2 * 262144);
  int*   counts= (int*)(tail + 3 * 262144);
  int*   off   = (int*)(tail + 3 * 262144 + 64);

  hipLaunchKernelGGL(init_counts, dim3(1), dim3(64), 0, stream, counts);
  hipLaunchKernelGGL(cvt_bf16, dim3(2048), dim3(256), 0, stream,
                     (const float4*)x, x_bf, (T_TOK * H_DIM) / 4);
  hipLaunchKernelGGL(cvt_bf16, dim3(4096), dim3(256), 0, stream,
                     (const float4*)wg, wg_bf, (NEXP * I_DIM * H_DIM) / 4);
  hipLaunchKernelGGL(cvt_bf16, dim3(4096), dim3(256), 0, stream,
                     (const float4*)wu, wu_bf, (NEXP * I_DIM * H_DIM) / 4);
  hipLaunchKernelGGL(cvt_bf16, dim3(4096), dim3(256), 0, stream,
                     (const float4*)wd, wd_bf, (NEXP * I_DIM * H_DIM) / 4);
  hipLaunchKernelGGL(zero_f32, dim3(4096), dim3(256), 0, stream, out, T_TOK * H_DIM);
  hipLaunchKernelGGL(router_kernel, dim3(T_TOK), dim3(512), 0, stream,
                     x, rw, probs, tok, wgt, counts);
  hipLaunchKernelGGL(scan_offsets, dim3(1), dim3(64), 0, stream, counts, off);
  hipLaunchKernelGGL(gemm1_kernel, dim3(I_DIM / 128, T_TOK / 128, NEXP), dim3(256), 0, stream,
                     x_bf, wg_bf, wu_bf, h_bf, tok, counts, off);
  hipLaunchKernelGGL(gemm2_kernel, dim3(H_DIM / 128, T_TOK / 128, NEXP), dim3(256), 0, stream,
                     h_bf, wd_bf, out, tok, wgt, counts, off);
  hipLaunchKernelGGL(finalize_kernel, dim3(1), dim3(512), 0, stream,
                     probs, out + (size_t)T_TOK * H_DIM);
}

// Round 2
// 961.658 us; speedup vs baseline: 1.3626x; 1.3626x over previous
//
#include <hip/hip_runtime.h>
#include <hip/hip_bf16.h>

#define T_TOK 8192
#define H_DIM 1024
#define I_DIM 4096
#define NEXP 8

typedef __bf16 bf16x8 __attribute__((ext_vector_type(8)));
typedef float f32x4 __attribute__((ext_vector_type(4)));
typedef unsigned short u16;

#define AS3(p) ((__attribute__((address_space(3))) void*)(p))
#define AS1(p) ((const __attribute__((address_space(1))) void*)(p))
#define GLDS16(src, dst) __builtin_amdgcn_global_load_lds(AS1(src), AS3(dst), 16, 0, 0)

__device__ __forceinline__ u16 f2bf(float f) {
  union { float f; unsigned u; } c; c.f = f;
  unsigned u = c.u;
  return (u16)((u + 0x7FFFu + ((u >> 16) & 1u)) >> 16);
}

__global__ void init_counts(int* counts) {
  if (threadIdx.x < NEXP) counts[threadIdx.x] = 0;
}

__global__ void cvt_bf16(const float4* __restrict__ in, u16* __restrict__ out, int n4) {
  int i = blockIdx.x * blockDim.x + threadIdx.x;
  int s = gridDim.x * blockDim.x;
  for (; i < n4; i += s) {
    float4 v = in[i];
    ushort4 o;
    o.x = f2bf(v.x); o.y = f2bf(v.y); o.z = f2bf(v.z); o.w = f2bf(v.w);
    *(ushort4*)(out + (size_t)i * 4) = o;
  }
}

// One block per token; 8 waves, wave e computes logit_e in fp64.
__global__ __launch_bounds__(512) void router_kernel(
    const float* __restrict__ x, const float* __restrict__ rw,
    float* __restrict__ probs, int* __restrict__ tok, float* __restrict__ wgt,
    int* __restrict__ counts, int4* __restrict__ ass)
{
  int t = blockIdx.x;
  int w = threadIdx.x >> 6, lane = threadIdx.x & 63;
  const float* xr = x + (size_t)t * H_DIM;
  const float* wr = rw + (size_t)w * H_DIM;
  double acc = 0.0;
  #pragma unroll
  for (int j = 0; j < H_DIM / 64; ++j) {
    int h = lane + 64 * j;
    acc += (double)xr[h] * (double)wr[h];
  }
  #pragma unroll
  for (int off = 32; off > 0; off >>= 1) acc += __shfl_down(acc, off);
  __shared__ double logits[NEXP];
  if (lane == 0) logits[w] = acc;
  __syncthreads();
  if (threadIdx.x == 0) {
    int i1 = 0;
    #pragma unroll
    for (int e = 1; e < NEXP; ++e) if (logits[e] > logits[i1]) i1 = e;
    int i2 = (i1 == 0) ? 1 : 0;
    #pragma unroll
    for (int e = 0; e < NEXP; ++e) {
      if (e == i1) continue;
      if (logits[e] > logits[i2]) i2 = e;
    }
    double l1 = logits[i1], l2 = logits[i2];
    float w1 = (float)(1.0 / (1.0 + exp(l2 - l1)));
    float w2 = 1.0f - w1;
    double m = l1, s = 0.0, p[NEXP];
    #pragma unroll
    for (int e = 0; e < NEXP; ++e) { p[e] = exp(logits[e] - m); s += p[e]; }
    #pragma unroll
    for (int e = 0; e < NEXP; ++e) probs[(size_t)t * NEXP + e] = (float)(p[e] / s);
    int p1 = atomicAdd(&counts[i1], 1);
    tok[i1 * T_TOK + p1] = t; wgt[i1 * T_TOK + p1] = w1;
    int p2 = atomicAdd(&counts[i2], 1);
    tok[i2 * T_TOK + p2] = t; wgt[i2 * T_TOK + p2] = w2;
    ass[t] = make_int4(i1, p1, i2, p2);
  }
}

__global__ void scan_offsets(const int* __restrict__ counts, int* __restrict__ off) {
  if (threadIdx.x == 0) {
    int s = 0;
    for (int e = 0; e < NEXP; ++e) { off[e] = s; s += counts[e]; }
  }
}

// Fused gate/up GEMM + SwiGLU. Block tile: 128 tokens x 64 h-cols.
// 4 waves (2M x 2N), wave tile 64 rows x 32 h-cols; per wave acc = gate 4x2 + up 4x2 = 64 regs.
__global__ __launch_bounds__(256, 2) void gemm1_kernel(
    const u16* __restrict__ x_bf, const u16* __restrict__ wg_bf,
    const u16* __restrict__ wu_bf, u16* __restrict__ h_bf,
    const int* __restrict__ tok, const int* __restrict__ counts,
    const int* __restrict__ off)
{
  int e = blockIdx.z;
  int cnt = counts[e];
  int mb = blockIdx.y * 128;
  if (mb >= cnt) return;
  int nb = blockIdx.x * 64;       // h-col base
  int tid = threadIdx.x;

  __shared__ u16 lds[128 * 32 + 64 * 32 + 64 * 32];  // A(8KB) G(4KB) U(4KB)
  u16* ldsA = lds;
  u16* ldsG = lds + 4096;
  u16* ldsU = lds + 6144;

  int srow = tid >> 2;          // 0..63
  int skp  = (tid & 3) * 8;     // k elems
  int t0 = tok[e * T_TOK + min(mb + srow, cnt - 1)];
  int t1 = tok[e * T_TOK + min(mb + srow + 64, cnt - 1)];
  const u16* a0 = x_bf + (size_t)t0 * H_DIM + skp;
  const u16* a1 = x_bf + (size_t)t1 * H_DIM + skp;
  const u16* g0 = wg_bf + (size_t)e * I_DIM * H_DIM + (size_t)(nb + srow) * H_DIM + skp;
  const u16* u0 = wu_bf + (size_t)e * I_DIM * H_DIM + (size_t)(nb + srow) * H_DIM + skp;

  int w = tid >> 6, lane = tid & 63;
  int wm = (w >> 1) * 64, wn = (w & 1) * 32;
  int lr = lane & 15, lk = (lane >> 4) * 8;

  f32x4 accg[4][2] = {};
  f32x4 accu[4][2] = {};

  for (int kk = 0; kk < H_DIM; kk += 32) {
    GLDS16(a0 + kk, ldsA + tid * 8);
    GLDS16(a1 + kk, ldsA + 2048 + tid * 8);
    GLDS16(g0 + kk, ldsG + tid * 8);
    GLDS16(u0 + kk, ldsU + tid * 8);
    __syncthreads();
    bf16x8 af[4], gf[2], uf[2];
    #pragma unroll
    for (int m = 0; m < 4; ++m)
      af[m] = *(const bf16x8*)&ldsA[(wm + m * 16 + lr) * 32 + lk];
    #pragma unroll
    for (int n = 0; n < 2; ++n) {
      gf[n] = *(const bf16x8*)&ldsG[(wn + n * 16 + lr) * 32 + lk];
      uf[n] = *(const bf16x8*)&ldsU[(wn + n * 16 + lr) * 32 + lk];
    }
    #pragma unroll
    for (int m = 0; m < 4; ++m) {
      #pragma unroll
      for (int n = 0; n < 2; ++n) {
        accg[m][n] = __builtin_amdgcn_mfma_f32_16x16x32_bf16(af[m], gf[n], accg[m][n], 0, 0, 0);
        accu[m][n] = __builtin_amdgcn_mfma_f32_16x16x32_bf16(af[m], uf[n], accu[m][n], 0, 0, 0);
      }
    }
    __syncthreads();
  }

  int ofs = off[e];
  #pragma unroll
  for (int m = 0; m < 4; ++m) {
    #pragma unroll
    for (int r = 0; r < 4; ++r) {
      int row = mb + wm + m * 16 + (lane >> 4) * 4 + r;
      if (row < cnt) {
        size_t base = (size_t)(ofs + row) * I_DIM + nb + wn;
        #pragma unroll
        for (int n = 0; n < 2; ++n) {
          float g = accg[m][n][r];
          float u = accu[m][n][r];
          float sg = g / (1.f + __expf(-g));
          h_bf[base + n * 16 + lr] = f2bf(sg * u);
        }
      }
    }
  }
}

// GEMM2: y = h @ wd[e]^T, weighted store into y_buf[pos][H] (f32, no atomics).
__global__ __launch_bounds__(256) void gemm2_kernel(
    const u16* __restrict__ h_bf, const u16* __restrict__ wd_bf,
    float* __restrict__ y_buf, const float* __restrict__ wgt,
    const int* __restrict__ counts, const int* __restrict__ off)
{
  int e = blockIdx.z;
  int cnt = counts[e];
  int mb = blockIdx.y * 128;
  if (mb >= cnt) return;
  int nb = blockIdx.x * 128;
  int tid = threadIdx.x;
  int ofs = off[e];

  __shared__ u16 lds[2 * 128 * 32];
  u16* ldsA = lds;
  u16* ldsB = lds + 4096;

  int srow = tid >> 2, skp = (tid & 3) * 8;
  int r0 = min(mb + srow, cnt - 1);
  int r1 = min(mb + srow + 64, cnt - 1);
  const u16* a0 = h_bf + (size_t)(ofs + r0) * I_DIM + skp;
  const u16* a1 = h_bf + (size_t)(ofs + r1) * I_DIM + skp;
  const u16* b0 = wd_bf + (size_t)e * H_DIM * I_DIM + (size_t)(nb + srow) * I_DIM + skp;
  const u16* b1 = b0 + (size_t)64 * I_DIM;

  int w = tid >> 6, lane = tid & 63;
  int wr = (w >> 1) * 64, wc = (w & 1) * 64;
  int lr = lane & 15, lk = (lane >> 4) * 8;

  f32x4 acc[4][4] = {};
  for (int kk = 0; kk < I_DIM; kk += 32) {
    GLDS16(a0 + kk, ldsA + tid * 8);
    GLDS16(a1 + kk, ldsA + 2048 + tid * 8);
    GLDS16(b0 + kk, ldsB + tid * 8);
    GLDS16(b1 + kk, ldsB + 2048 + tid * 8);
    __syncthreads();
    bf16x8 af[4], bfr[4];
    #pragma unroll
    for (int m = 0; m < 4; ++m)
      af[m] = *(const bf16x8*)&ldsA[(wr + m * 16 + lr) * 32 + lk];
    #pragma unroll
    for (int n = 0; n < 4; ++n)
      bfr[n] = *(const bf16x8*)&ldsB[(wc + n * 16 + lr) * 32 + lk];
    #pragma unroll
    for (int m = 0; m < 4; ++m) {
      #pragma unroll
      for (int n = 0; n < 4; ++n)
        acc[m][n] = __builtin_amdgcn_mfma_f32_16x16x32_bf16(af[m], bfr[n], acc[m][n], 0, 0, 0);
    }
    __syncthreads();
  }

  #pragma unroll
  for (int m = 0; m < 4; ++m) {
    #pragma unroll
    for (int r = 0; r < 4; ++r) {
      int pos = mb + wr + m * 16 + (lane >> 4) * 4 + r;
      if (pos < cnt) {
        float wt = wgt[e * T_TOK + pos];
        size_t base = (size_t)(ofs + pos) * H_DIM + nb + wc;
        #pragma unroll
        for (int n = 0; n < 4; ++n)
          y_buf[base + n * 16 + lr] = wt * acc[m][n][r];
      }
    }
  }
}

// out[t] = y_buf[off[e1]+p1] + y_buf[off[e2]+p2]  (float4 vectorized)
__global__ __launch_bounds__(256) void combine_kernel(
    const float* __restrict__ y_buf, const int4* __restrict__ ass,
    const int* __restrict__ off, float* __restrict__ out)
{
  int idx = blockIdx.x * blockDim.x + threadIdx.x;   // T_TOK * H/4 items
  int t = idx >> 8;            // H/4 = 256
  int h4 = (idx & 255) * 4;
  int4 a = ass[t];
  size_t p1 = (size_t)(off[a.x] + a.y) * H_DIM + h4;
  size_t p2 = (size_t)(off[a.z] + a.w) * H_DIM + h4;
  float4 v1 = *(const float4*)(y_buf + p1);
  float4 v2 = *(const float4*)(y_buf + p2);
  float4 o;
  o.x = v1.x + v2.x; o.y = v1.y + v2.y; o.z = v1.z + v2.z; o.w = v1.w + v2.w;
  *(float4*)(out + (size_t)t * H_DIM + h4) = o;
}

__global__ __launch_bounds__(512) void finalize_kernel(
    const float* __restrict__ probs, float* __restrict__ aux_out)
{
  __shared__ double part[512];
  int tid = threadIdx.x;
  int e = tid & 7;
  double s = 0.0;
  for (int t = tid >> 3; t < T_TOK; t += 64) s += probs[(size_t)t * NEXP + e];
  part[tid] = s;
  __syncthreads();
  if (tid < 8) {
    double u = 0.0;
    for (int i = tid; i < 512; i += 8) u += part[i];
    part[tid] = u;
  }
  __syncthreads();
  if (tid == 0) {
    double tot = 0.0;
    for (int k = 0; k < 8; ++k) tot += part[k];
    double aux = 0.0;
    for (int k = 0; k < 8; ++k) {
      double d = part[k] / tot - 0.125;
      aux += d * d;
    }
    aux_out[0] = (float)(0.01 * aux / 8.0);
  }
}

extern "C" void kernel_launch(void* const* d_in, const int* in_sizes, int n_in,
                              void* d_out, int out_size, void* d_ws, size_t ws_size,
                              hipStream_t stream) {
  const float* x  = (const float*)d_in[0];
  const float* rw = (const float*)d_in[1];
  const float* wg = (const float*)d_in[2];
  const float* wu = (const float*)d_in[3];
  const float* wd = (const float*)d_in[4];
  float* out = (float*)d_out;

  char* ws = (char*)d_ws;
  const size_t SZ_X  = (size_t)T_TOK * H_DIM * 2;            // 16 MB
  const size_t SZ_W  = (size_t)NEXP * I_DIM * H_DIM * 2;     // 64 MB each
  const size_t SZ_H  = (size_t)(2 * T_TOK + 128) * I_DIM * 2;
  u16* x_bf  = (u16*)(ws);
  u16* wg_bf = (u16*)(ws + SZ_X);
  u16* wu_bf = (u16*)(ws + SZ_X + SZ_W);
  u16* wd_bf = (u16*)(ws + SZ_X + 2 * SZ_W);
  u16* h_bf  = (u16*)(ws + SZ_X + 3 * SZ_W);
  // y_buf (f32, 2*T_TOK x H = 67 MB) aliases wg_bf+wu_bf (dead after gemm1)
  float* y_buf = (float*)(ws + SZ_X);
  char* tail = ws + SZ_X + 3 * SZ_W + SZ_H;
  float* probs = (float*)tail;
  int*   tok   = (int*)(tail + 262144);
  float* wgt   = (float*)(tail + 2 * 262144);
  int*   counts= (int*)(tail + 3 * 262144);
  int*   off   = (int*)(tail + 3 * 262144 + 64);
  int4*  ass   = (int4*)(tail + 3 * 262144 + 128);

  hipLaunchKernelGGL(init_counts, dim3(1), dim3(64), 0, stream, counts);
  hipLaunchKernelGGL(cvt_bf16, dim3(2048), dim3(256), 0, stream,
                     (const float4*)x, x_bf, (T_TOK * H_DIM) / 4);
  hipLaunchKernelGGL(cvt_bf16, dim3(4096), dim3(256), 0, stream,
                     (const float4*)wg, wg_bf, (NEXP * I_DIM * H_DIM) / 4);
  hipLaunchKernelGGL(cvt_bf16, dim3(4096), dim3(256), 0, stream,
                     (const float4*)wu, wu_bf, (NEXP * I_DIM * H_DIM) / 4);
  hipLaunchKernelGGL(cvt_bf16, dim3(4096), dim3(256), 0, stream,
                     (const float4*)wd, wd_bf, (NEXP * I_DIM * H_DIM) / 4);
  hipLaunchKernelGGL(router_kernel, dim3(T_TOK), dim3(512), 0, stream,
                     x, rw, probs, tok, wgt, counts, ass);
  hipLaunchKernelGGL(scan_offsets, dim3(1), dim3(64), 0, stream, counts, off);
  hipLaunchKernelGGL(gemm1_kernel, dim3(I_DIM / 64, T_TOK / 128, NEXP), dim3(256), 0, stream,
                     x_bf, wg_bf, wu_bf, h_bf, tok, counts, off);
  hipLaunchKernelGGL(gemm2_kernel, dim3(H_DIM / 128, T_TOK / 128, NEXP), dim3(256), 0, stream,
                     h_bf, wd_bf, y_buf, wgt, counts, off);
  hipLaunchKernelGGL(combine_kernel, dim3(T_TOK * (H_DIM / 4) / 256), dim3(256), 0, stream,
                     y_buf, ass, off, out);
  hipLaunchKernelGGL(finalize_kernel, dim3(1), dim3(512), 0, stream,
                     probs, out + (size_t)T_TOK * H_DIM);
}

// Round 3
// 924.109 us; speedup vs baseline: 1.4179x; 1.0406x over previous
//
#include <hip/hip_runtime.h>
#include <hip/hip_bf16.h>

#define T_TOK 8192
#define H_DIM 1024
#define I_DIM 4096
#define NEXP 8

typedef __bf16 bf16x8 __attribute__((ext_vector_type(8)));
typedef float f32x4 __attribute__((ext_vector_type(4)));
typedef unsigned short u16;

#define AS3(p) ((__attribute__((address_space(3))) void*)(p))
#define AS1(p) ((const __attribute__((address_space(1))) void*)(p))
#define GLDS16(src, dst) __builtin_amdgcn_global_load_lds(AS1(src), AS3(dst), 16, 0, 0)

#define BAR() asm volatile("s_barrier" ::: "memory")
#define VMC(n) asm volatile("s_waitcnt vmcnt(" #n ")" ::: "memory")

__device__ __forceinline__ u16 f2bf(float f) {
  union { float f; unsigned u; } c; c.f = f;
  unsigned u = c.u;
  return (u16)((u + 0x7FFFu + ((u >> 16) & 1u)) >> 16);
}

__global__ void init_counts(int* counts) {
  if (threadIdx.x < NEXP) counts[threadIdx.x] = 0;
}

__global__ void cvt_bf16(const float4* __restrict__ in, u16* __restrict__ out, int n4) {
  int i = blockIdx.x * blockDim.x + threadIdx.x;
  int s = gridDim.x * blockDim.x;
  for (; i < n4; i += s) {
    float4 v = in[i];
    ushort4 o;
    o.x = f2bf(v.x); o.y = f2bf(v.y); o.z = f2bf(v.z); o.w = f2bf(v.w);
    *(ushort4*)(out + (size_t)i * 4) = o;
  }
}

// One block per token; 8 waves, wave e computes logit_e in fp64.
__global__ __launch_bounds__(512) void router_kernel(
    const float* __restrict__ x, const float* __restrict__ rw,
    float* __restrict__ probs, int* __restrict__ tok, float* __restrict__ wgt,
    int* __restrict__ counts, int4* __restrict__ ass)
{
  int t = blockIdx.x;
  int w = threadIdx.x >> 6, lane = threadIdx.x & 63;
  const float* xr = x + (size_t)t * H_DIM;
  const float* wr = rw + (size_t)w * H_DIM;
  double acc = 0.0;
  #pragma unroll
  for (int j = 0; j < H_DIM / 64; ++j) {
    int h = lane + 64 * j;
    acc += (double)xr[h] * (double)wr[h];
  }
  #pragma unroll
  for (int off = 32; off > 0; off >>= 1) acc += __shfl_down(acc, off);
  __shared__ double logits[NEXP];
  if (lane == 0) logits[w] = acc;
  __syncthreads();
  if (threadIdx.x == 0) {
    int i1 = 0;
    #pragma unroll
    for (int e = 1; e < NEXP; ++e) if (logits[e] > logits[i1]) i1 = e;
    int i2 = (i1 == 0) ? 1 : 0;
    #pragma unroll
    for (int e = 0; e < NEXP; ++e) {
      if (e == i1) continue;
      if (logits[e] > logits[i2]) i2 = e;
    }
    double l1 = logits[i1], l2 = logits[i2];
    float w1 = (float)(1.0 / (1.0 + exp(l2 - l1)));
    float w2 = 1.0f - w1;
    double m = l1, s = 0.0, p[NEXP];
    #pragma unroll
    for (int e = 0; e < NEXP; ++e) { p[e] = exp(logits[e] - m); s += p[e]; }
    #pragma unroll
    for (int e = 0; e < NEXP; ++e) probs[(size_t)t * NEXP + e] = (float)(p[e] / s);
    int p1 = atomicAdd(&counts[i1], 1);
    tok[i1 * T_TOK + p1] = t; wgt[i1 * T_TOK + p1] = w1;
    int p2 = atomicAdd(&counts[i2], 1);
    tok[i2 * T_TOK + p2] = t; wgt[i2 * T_TOK + p2] = w2;
    ass[t] = make_int4(i1, p1, i2, p2);
  }
}

__global__ void scan_offsets(const int* __restrict__ counts, int* __restrict__ off) {
  if (threadIdx.x == 0) {
    int s = 0;
    for (int e = 0; e < NEXP; ++e) { off[e] = s; s += counts[e]; }
  }
}

// ---------------- GEMM1: 8-phase 256x(128h as 256 virtual) BK=64 ----------------
// A: gathered tokens [256,64] per K-tile. B virtual rows: 0..127 = wg[hb..hb+128),
// 128..255 = wu[hb..hb+128). Wave (wm,wn): rows wm*128.., vcols wn*16 + j*64 (j=0..3)
// => j in {0,1} gate, {2,3} up at the SAME h-cols -> in-register SwiGLU.
// LDS per buf: A 32KB @0, B 32KB @32768; 2 bufs (stride 65536) = 128KB.
// Swizzle: LDS byte (row,c) holds source col-byte c ^ ((row&7)<<4).

#define DS_A1(bb, qm) { \
  _Pragma("unroll") for (int ms = 0; ms < 4; ++ms) { \
  _Pragma("unroll") for (int ks = 0; ks < 2; ++ks) \
    af[ms][ks] = *(const bf16x8*)(lds + (bb) + aoff + ((qm)*64 + ms*16)*128 + ((ks<<6) ^ k0b)); } }

#define DS_B1(bb, qn) { \
  _Pragma("unroll") for (int js = 0; js < 2; ++js) { \
  _Pragma("unroll") for (int ks = 0; ks < 2; ++ks) \
    bfr[js][ks] = *(const bf16x8*)(lds + (bb) + boff + ((qn)*128 + js*64)*128 + ((ks<<6) ^ k0b)); } }

#define MM1(qm, qn) { \
  __builtin_amdgcn_s_setprio(1); \
  _Pragma("unroll") for (int ms = 0; ms < 4; ++ms) { \
  _Pragma("unroll") for (int js = 0; js < 2; ++js) { \
  _Pragma("unroll") for (int ks = 0; ks < 2; ++ks) \
    acc[(qm)*4+ms][(qn)*2+js] = __builtin_amdgcn_mfma_f32_16x16x32_bf16( \
        af[ms][ks], bfr[js][ks], acc[(qm)*4+ms][(qn)*2+js], 0, 0, 0); } } \
  __builtin_amdgcn_s_setprio(0); }

#define STG1_A0(db) { GLDS16(pA[0], lds + (db) + dstLane); GLDS16(pA[1], lds + (db) + 8192 + dstLane); }
#define STG1_A1(db) { GLDS16(pA[2], lds + (db) + 16384 + dstLane); GLDS16(pA[3], lds + (db) + 24576 + dstLane); }
#define STG1_B0(db) { GLDS16(pG[0], lds + (db) + 32768 + dstLane); GLDS16(pG[1], lds + (db) + 40960 + dstLane); }
#define STG1_B1(db) { GLDS16(pU[0], lds + (db) + 49152 + dstLane); GLDS16(pU[1], lds + (db) + 57344 + dstLane); }
#define ADV1() { pA[0]+=64; pA[1]+=64; pA[2]+=64; pA[3]+=64; pG[0]+=64; pG[1]+=64; pU[0]+=64; pU[1]+=64; }

__global__ __launch_bounds__(512) void gemm1_kernel(
    const u16* __restrict__ x_bf, const u16* __restrict__ wg_bf,
    const u16* __restrict__ wu_bf, u16* __restrict__ h_bf,
    const int* __restrict__ tok, const int* __restrict__ counts,
    const int* __restrict__ off)
{
  int e = blockIdx.z;
  int cnt = counts[e];
  int mb = blockIdx.y * 256;
  if (mb >= cnt) return;
  int hb = blockIdx.x * 128;
  int tid = threadIdx.x;

  __shared__ __align__(16) unsigned char lds[131072];

  // staging source pointers (pre-swizzled global addresses, linear LDS dest)
  int rloc = tid >> 3;
  int cbyte = (tid & 7) * 16;
  unsigned dstLane = tid * 16;

  const u16* pA[4];
  #pragma unroll
  for (int h = 0; h < 2; ++h) {
    #pragma unroll
    for (int i = 0; i < 2; ++i) {
      int r = h * 128 + i * 64 + rloc;
      int cp = cbyte ^ ((r & 7) << 4);
      int tk = tok[e * T_TOK + min(mb + r, cnt - 1)];
      pA[h * 2 + i] = x_bf + (size_t)tk * H_DIM + (cp >> 1);
    }
  }
  const u16* pG[2]; const u16* pU[2];
  #pragma unroll
  for (int i = 0; i < 2; ++i) {
    int r = i * 64 + rloc;
    int cp = cbyte ^ ((r & 7) << 4);
    pG[i] = wg_bf + (size_t)e * I_DIM * H_DIM + (size_t)(hb + r) * H_DIM + (cp >> 1);
    pU[i] = wu_bf + (size_t)e * I_DIM * H_DIM + (size_t)(hb + r) * H_DIM + (cp >> 1);
  }

  int wave = tid >> 6, lane = tid & 63;
  int wm = wave >> 2, wn = wave & 3;
  int lr = lane & 15;
  int k0b = ((lane >> 4) * 16) ^ ((lr & 7) << 4);
  unsigned aoff = (unsigned)(wm * 128 + lr) * 128;
  unsigned boff = 32768u + (unsigned)(wn * 16 + lr) * 128;

  f32x4 acc[8][4] = {};
  bf16x8 af[4][2], bfr[2][2];

  // prologue: stage K-tile 0 into buf0
  STG1_A0(0) STG1_A1(0) STG1_B0(0) STG1_B1(0)
  ADV1()

  const int NT = H_DIM / 64;  // 16
  #pragma unroll 2
  for (int t = 0; t < NT - 1; ++t) {
    unsigned cb = (unsigned)(t & 1) * 65536u;
    unsigned sb = 65536u - cb;
    // ph0 (qm0,qn0)
    STG1_A0(sb) VMC(4); BAR();
    DS_A1(cb, 0) DS_B1(cb, 0) MM1(0, 0) BAR();
    // ph1 (qm1,qn0)
    DS_A1(cb, 1) STG1_A1(sb) BAR();
    MM1(1, 0) BAR();
    // ph2 (qm1,qn1)
    STG1_B0(sb) VMC(6); BAR();
    DS_B1(cb, 1) MM1(1, 1) BAR();
    // ph3 (qm0,qn1)
    DS_A1(cb, 0) STG1_B1(sb) BAR();
    MM1(0, 1) BAR();
    ADV1()
  }
  { // final tile (no staging)
    unsigned cb = (unsigned)((NT - 1) & 1) * 65536u;
    VMC(2); BAR();
    DS_A1(cb, 0) DS_B1(cb, 0) MM1(0, 0) BAR();
    DS_A1(cb, 1) BAR(); MM1(1, 0) BAR();
    VMC(0); BAR();
    DS_B1(cb, 1) MM1(1, 1) BAR();
    DS_A1(cb, 0) MM1(0, 1)
  }

  // epilogue: in-register SwiGLU (gate j, up j+2 share (row,h))
  int ofs = off[e];
  int rr = (lane >> 4) * 4;
  #pragma unroll
  for (int mf = 0; mf < 8; ++mf) {
    #pragma unroll
    for (int r = 0; r < 4; ++r) {
      int row = mb + wm * 128 + mf * 16 + rr + r;
      if (row < cnt) {
        size_t base = (size_t)(ofs + row) * I_DIM + hb + wn * 16 + lr;
        #pragma unroll
        for (int j = 0; j < 2; ++j) {
          float g = acc[mf][j][r];
          float u = acc[mf][j + 2][r];
          float sg = g / (1.f + __expf(-g));
          h_bf[base + j * 64] = f2bf(sg * u);
        }
      }
    }
  }
}

// ---------------- GEMM2: 8-phase 256x128 BK=64, K=4096 ----------------
// LDS per buf: A 32KB @0, B 16KB @32768; stride 49152 = 96KB total.
// Wave (wm,wn): rows wm*128 (8 m-frags), cols wn*16 + j*64 (j=0,1).

#define DS2_A(bb, qq) { \
  _Pragma("unroll") for (int ms = 0; ms < 2; ++ms) { \
  _Pragma("unroll") for (int ks = 0; ks < 2; ++ks) \
    af2[ms][ks] = *(const bf16x8*)(lds + (bb) + aoff + ((qq)*32 + ms*16)*128 + ((ks<<6) ^ k0b)); } }

#define DS2_B(bb) { \
  _Pragma("unroll") for (int js = 0; js < 2; ++js) { \
  _Pragma("unroll") for (int ks = 0; ks < 2; ++ks) \
    bf2[js][ks] = *(const bf16x8*)(lds + (bb) + boff + (js*64)*128 + ((ks<<6) ^ k0b)); } }

#define MM2(qq) { \
  __builtin_amdgcn_s_setprio(1); \
  _Pragma("unroll") for (int ms = 0; ms < 2; ++ms) { \
  _Pragma("unroll") for (int js = 0; js < 2; ++js) { \
  _Pragma("unroll") for (int ks = 0; ks < 2; ++ks) \
    acc2[(qq)*2+ms][js] = __builtin_amdgcn_mfma_f32_16x16x32_bf16( \
        af2[ms][ks], bf2[js][ks], acc2[(qq)*2+ms][js], 0, 0, 0); } } \
  __builtin_amdgcn_s_setprio(0); }

#define STG2_A0(db) { GLDS16(qA[0], lds + (db) + dstLane); GLDS16(qA[1], lds + (db) + 8192 + dstLane); }
#define STG2_A1(db) { GLDS16(qA[2], lds + (db) + 16384 + dstLane); GLDS16(qA[3], lds + (db) + 24576 + dstLane); }
#define STG2_B(db)  { GLDS16(qB[0], lds + (db) + 32768 + dstLane); GLDS16(qB[1], lds + (db) + 40960 + dstLane); }
#define ADV2() { qA[0]+=64; qA[1]+=64; qA[2]+=64; qA[3]+=64; qB[0]+=64; qB[1]+=64; }

__global__ __launch_bounds__(512) void gemm2_kernel(
    const u16* __restrict__ h_bf, const u16* __restrict__ wd_bf,
    float* __restrict__ y_buf, const float* __restrict__ wgt,
    const int* __restrict__ counts, const int* __restrict__ off)
{
  int e = blockIdx.z;
  int cnt = counts[e];
  int mb = blockIdx.y * 256;
  if (mb >= cnt) return;
  int nb = blockIdx.x * 128;
  int tid = threadIdx.x;
  int ofs = off[e];

  __shared__ __align__(16) unsigned char lds[98304];

  int rloc = tid >> 3;
  int cbyte = (tid & 7) * 16;
  unsigned dstLane = tid * 16;

  const u16* qA[4];
  #pragma unroll
  for (int h = 0; h < 2; ++h) {
    #pragma unroll
    for (int i = 0; i < 2; ++i) {
      int r = h * 128 + i * 64 + rloc;
      int cp = cbyte ^ ((r & 7) << 4);
      int rowi = ofs + min(mb + r, cnt - 1);
      qA[h * 2 + i] = h_bf + (size_t)rowi * I_DIM + (cp >> 1);
    }
  }
  const u16* qB[2];
  #pragma unroll
  for (int i = 0; i < 2; ++i) {
    int r = i * 64 + rloc;
    int cp = cbyte ^ ((r & 7) << 4);
    qB[i] = wd_bf + (size_t)e * H_DIM * I_DIM + (size_t)(nb + r) * I_DIM + (cp >> 1);
  }

  int wave = tid >> 6, lane = tid & 63;
  int wm = wave >> 2, wn = wave & 3;
  int lr = lane & 15;
  int k0b = ((lane >> 4) * 16) ^ ((lr & 7) << 4);
  unsigned aoff = (unsigned)(wm * 128 + lr) * 128;
  unsigned boff = 32768u + (unsigned)(wn * 16 + lr) * 128;

  f32x4 acc2[8][2] = {};
  bf16x8 af2[2][2], bf2[2][2];

  STG2_A0(0) STG2_A1(0) STG2_B(0)
  ADV2()

  const int NT = I_DIM / 64;  // 64
  #pragma unroll 2
  for (int t = 0; t < NT - 1; ++t) {
    unsigned cb = (unsigned)(t & 1) * 49152u;
    unsigned sb = 49152u - cb;
    // ph0
    STG2_A0(sb) VMC(2); BAR();
    DS2_A(cb, 0) DS2_B(cb) MM2(0) BAR();
    // ph1
    DS2_A(cb, 1) STG2_A1(sb) BAR();
    MM2(1) BAR();
    // ph2
    DS2_A(cb, 2) STG2_B(sb) BAR();
    MM2(2) BAR();
    // ph3
    DS2_A(cb, 3) BAR();
    MM2(3) BAR();
    ADV2()
  }
  { // final tile
    unsigned cb = (unsigned)((NT - 1) & 1) * 49152u;
    VMC(0); BAR();
    DS2_A(cb, 0) DS2_B(cb) MM2(0) BAR();
    DS2_A(cb, 1) BAR(); MM2(1) BAR();
    DS2_A(cb, 2) BAR(); MM2(2) BAR();
    DS2_A(cb, 3) MM2(3)
  }

  int rr = (lane >> 4) * 4;
  #pragma unroll
  for (int mf = 0; mf < 8; ++mf) {
    #pragma unroll
    for (int r = 0; r < 4; ++r) {
      int pos = mb + wm * 128 + mf * 16 + rr + r;
      if (pos < cnt) {
        float wt = wgt[e * T_TOK + pos];
        size_t base = (size_t)(ofs + pos) * H_DIM + nb + wn * 16 + lr;
        #pragma unroll
        for (int j = 0; j < 2; ++j)
          y_buf[base + j * 64] = wt * acc2[mf][j][r];
      }
    }
  }
}

// out[t] = y_buf[off[e1]+p1] + y_buf[off[e2]+p2]  (float4 vectorized)
__global__ __launch_bounds__(256) void combine_kernel(
    const float* __restrict__ y_buf, const int4* __restrict__ ass,
    const int* __restrict__ off, float* __restrict__ out)
{
  int idx = blockIdx.x * blockDim.x + threadIdx.x;
  int t = idx >> 8;
  int h4 = (idx & 255) * 4;
  int4 a = ass[t];
  size_t p1 = (size_t)(off[a.x] + a.y) * H_DIM + h4;
  size_t p2 = (size_t)(off[a.z] + a.w) * H_DIM + h4;
  float4 v1 = *(const float4*)(y_buf + p1);
  float4 v2 = *(const float4*)(y_buf + p2);
  float4 o;
  o.x = v1.x + v2.x; o.y = v1.y + v2.y; o.z = v1.z + v2.z; o.w = v1.w + v2.w;
  *(float4*)(out + (size_t)t * H_DIM + h4) = o;
}

__global__ __launch_bounds__(512) void finalize_kernel(
    const float* __restrict__ probs, float* __restrict__ aux_out)
{
  __shared__ double part[512];
  int tid = threadIdx.x;
  int e = tid & 7;
  double s = 0.0;
  for (int t = tid >> 3; t < T_TOK; t += 64) s += probs[(size_t)t * NEXP + e];
  part[tid] = s;
  __syncthreads();
  if (tid < 8) {
    double u = 0.0;
    for (int i = tid; i < 512; i += 8) u += part[i];
    part[tid] = u;
  }
  __syncthreads();
  if (tid == 0) {
    double tot = 0.0;
    for (int k = 0; k < 8; ++k) tot += part[k];
    double aux = 0.0;
    for (int k = 0; k < 8; ++k) {
      double d = part[k] / tot - 0.125;
      aux += d * d;
    }
    aux_out[0] = (float)(0.01 * aux / 8.0);
  }
}

extern "C" void kernel_launch(void* const* d_in, const int* in_sizes, int n_in,
                              void* d_out, int out_size, void* d_ws, size_t ws_size,
                              hipStream_t stream) {
  const float* x  = (const float*)d_in[0];
  const float* rw = (const float*)d_in[1];
  const float* wg = (const float*)d_in[2];
  const float* wu = (const float*)d_in[3];
  const float* wd = (const float*)d_in[4];
  float* out = (float*)d_out;

  char* ws = (char*)d_ws;
  const size_t SZ_X  = (size_t)T_TOK * H_DIM * 2;            // 16 MB
  const size_t SZ_W  = (size_t)NEXP * I_DIM * H_DIM * 2;     // 64 MB each
  const size_t SZ_H  = (size_t)(2 * T_TOK + 256) * I_DIM * 2;
  u16* x_bf  = (u16*)(ws);
  u16* wg_bf = (u16*)(ws + SZ_X);
  u16* wu_bf = (u16*)(ws + SZ_X + SZ_W);
  u16* wd_bf = (u16*)(ws + SZ_X + 2 * SZ_W);
  u16* h_bf  = (u16*)(ws + SZ_X + 3 * SZ_W);
  // y_buf (f32, 2*T_TOK x H = 67 MB) aliases wg_bf+wu_bf (dead after gemm1)
  float* y_buf = (float*)(ws + SZ_X);
  char* tail = ws + SZ_X + 3 * SZ_W + SZ_H;
  float* probs = (float*)tail;
  int*   tok   = (int*)(tail + 262144);
  float* wgt   = (float*)(tail + 2 * 262144);
  int*   counts= (int*)(tail + 3 * 262144);
  int*   off   = (int*)(tail + 3 * 262144 + 64);
  int4*  ass   = (int4*)(tail + 3 * 262144 + 128);

  hipLaunchKernelGGL(init_counts, dim3(1), dim3(64), 0, stream, counts);
  hipLaunchKernelGGL(cvt_bf16, dim3(2048), dim3(256), 0, stream,
                     (const float4*)x, x_bf, (T_TOK * H_DIM) / 4);
  hipLaunchKernelGGL(cvt_bf16, dim3(4096), dim3(256), 0, stream,
                     (const float4*)wg, wg_bf, (NEXP * I_DIM * H_DIM) / 4);
  hipLaunchKernelGGL(cvt_bf16, dim3(4096), dim3(256), 0, stream,
                     (const float4*)wu, wu_bf, (NEXP * I_DIM * H_DIM) / 4);
  hipLaunchKernelGGL(cvt_bf16, dim3(4096), dim3(256), 0, stream,
                     (const float4*)wd, wd_bf, (NEXP * I_DIM * H_DIM) / 4);
  hipLaunchKernelGGL(router_kernel, dim3(T_TOK), dim3(512), 0, stream,
                     x, rw, probs, tok, wgt, counts, ass);
  hipLaunchKernelGGL(scan_offsets, dim3(1), dim3(64), 0, stream, counts, off);
  hipLaunchKernelGGL(gemm1_kernel, dim3(I_DIM / 128, 32, NEXP), dim3(512), 0, stream,
                     x_bf, wg_bf, wu_bf, h_bf, tok, counts, off);
  hipLaunchKernelGGL(gemm2_kernel, dim3(H_DIM / 128, 32, NEXP), dim3(512), 0, stream,
                     h_bf, wd_bf, y_buf, wgt, counts, off);
  hipLaunchKernelGGL(combine_kernel, dim3(T_TOK * (H_DIM / 4) / 256), dim3(256), 0, stream,
                     y_buf, ass, off, out);
  hipLaunchKernelGGL(finalize_kernel, dim3(1), dim3(512), 0, stream,
                     probs, out + (size_t)T_TOK * H_DIM);
}